// Round 3
// baseline (508.969 us; speedup 1.0000x reference)
//
#include <hip/hip_runtime.h>
#include <stdint.h>

#define TT 50
#define NSTEP 49
#define NBATCH 4096
#define SS 100
#define HH 256
#define K1 128      // padded K for GEMM1 (S=100 -> 128)
#define NO 128      // padded N for GEMM3 (C=100 -> 128)
#define MROWS 16
#define NBLK 256
#define NTHR 512    // 8 waves

typedef short bf16x8 __attribute__((ext_vector_type(8)));
typedef float f32x4 __attribute__((ext_vector_type(4)));

#define MFMA(a, b, c) __builtin_amdgcn_mfma_f32_16x16x32_bf16((a), (b), (c), 0, 0, 0)

// LDS-only barrier: waits ds ops (lgkmcnt) but does NOT drain vmcnt, so
// register prefetches of read-only globals (weights/prices) stay in flight
// across the sync. __syncthreads()'s workgroup fence would emit
// s_waitcnt vmcnt(0) and kill the software pipeline.
__device__ __forceinline__ void bar_lds() {
  __asm__ volatile("s_waitcnt lgkmcnt(0)\n\ts_barrier" ::: "memory");
}

__device__ __forceinline__ short f2b(float f) {
  union { float f; uint32_t u; } v;
  v.f = f;
  return (short)((v.u + 0x7FFFu + ((v.u >> 16) & 1u)) >> 16);
}

__device__ __forceinline__ bf16x8 cvt8(const float* __restrict__ p) {
  bf16x8 r;
#pragma unroll
  for (int j = 0; j < 8; ++j) r[j] = f2b(p[j]);
  return r;
}

__device__ __forceinline__ bf16x8 ldpad(const float* __restrict__ rowp, int k, int kmax) {
  bf16x8 r;
#pragma unroll
  for (int j = 0; j < 8; ++j) {
    int kk = k + j;
    r[j] = (kk < kmax) ? f2b(rowp[kk]) : (short)0;
  }
  return r;
}

__global__ void zero_out(float* out) {
  if (threadIdx.x == 0 && blockIdx.x == 0) out[0] = 0.f;
}

// Pre-convert weights fp32 -> bf16 with K/N padding baked in; also zero the output.
__global__ void prep(const float* __restrict__ W1, const float* __restrict__ W2,
                     const float* __restrict__ Wo,
                     short* __restrict__ W1b, short* __restrict__ W2b, short* __restrict__ Wob,
                     float* __restrict__ out) {
  const int stride = gridDim.x * blockDim.x;
  const int i = blockIdx.x * blockDim.x + threadIdx.x;
  const int n1 = TT * HH * K1;   // [t][h][k<=128]
  const int n2 = TT * HH * HH;   // [t][h][k]
  const int n3 = TT * NO * HH;   // [t][n<=128][k]
  for (int j = i; j < n1; j += stride) {
    int k = j & (K1 - 1);
    int r = j >> 7;  // t*HH + h
    W1b[j] = (k < SS) ? f2b(W1[r * SS + k]) : (short)0;
  }
  for (int j = i; j < n2; j += stride) W2b[j] = f2b(W2[j]);
  for (int j = i; j < n3; j += stride) {
    int k = j & (HH - 1);
    int rc = (j >> 8) & (NO - 1);
    int t = j >> 15;  // NO*HH = 32768
    Wob[j] = (rc < SS) ? f2b(Wo[(t * SS + rc) * HH + k]) : (short)0;
  }
  if (i == 0) out[0] = 0.f;
}

// Persistent kernel: each block owns MROWS batch rows for all NSTEP steps.
// s carry in per-thread registers; cost in a register accumulator.
// Deep software pipeline: W2[t] prefetched across LN1, Wo[t] across LN2,
// W1[t+1] + prices[t+1] across the step epilogue — enabled by bar_lds().
template <int MODE>
__global__ __launch_bounds__(NTHR, 2) void run_kernel(
    const float* __restrict__ s0, const float* __restrict__ prices,
    const float* __restrict__ b1, const float* __restrict__ g1, const float* __restrict__ be1,
    const float* __restrict__ b2, const float* __restrict__ g2, const float* __restrict__ be2,
    const float* __restrict__ bo,
    const float* __restrict__ W1f, const float* __restrict__ W2f, const float* __restrict__ Wof,
    const short* __restrict__ W1b, const short* __restrict__ W2b, const short* __restrict__ Wob,
    float* __restrict__ out) {
  __shared__ short sbuf[MROWS][K1 + 8];   // bf16 s, K-padded
  __shared__ short xb1[MROWS][HH + 8];
  __shared__ short xb2[MROWS][HH + 8];
  __shared__ float lnred[MROWS][17];      // stride 17 -> conflict-free row reads
  __shared__ float wsum[8];

  const int tid = threadIdx.x;
  const int w = tid >> 6;
  const int lane = tid & 63;
  const int q = lane >> 4;
  const int c16 = lane & 15;
  const int b0 = blockIdx.x * MROWS;

  const int n0 = w * 32 + c16;   // GEMM1/2 n-tile cols
  const int n1 = n0 + 16;
  const int col = w * 16 + c16;  // GEMM3 / epilogue col
  const bool cvalid = col < SS;

  for (int j = tid; j < MROWS * (K1 + 8); j += NTHR) ((short*)sbuf)[j] = 0;
  __syncthreads();

  float s_reg[4];
#pragma unroll
  for (int r = 0; r < 4; ++r) {
    int row = q * 4 + r;
    s_reg[r] = cvalid ? s0[(size_t)(b0 + row) * SS + col] : 0.f;
    if (cvalid) sbuf[row][col] = f2b(s_reg[r]);
  }
  __syncthreads();

  bf16x8 w1f[8];
  auto loadW1 = [&](int t) {
#pragma unroll
    for (int ks = 0; ks < 4; ++ks) {
      const int k = ks * 32 + q * 8;
      if (MODE == 0) {
        w1f[2 * ks + 0] = *(const bf16x8*)&W1b[((size_t)t * HH + n0) * K1 + k];
        w1f[2 * ks + 1] = *(const bf16x8*)&W1b[((size_t)t * HH + n1) * K1 + k];
      } else {
        w1f[2 * ks + 0] = ldpad(W1f + ((size_t)t * HH + n0) * SS, k, SS);
        w1f[2 * ks + 1] = ldpad(W1f + ((size_t)t * HH + n1) * SS, k, SS);
      }
    }
  };
  float pr[4];
  auto loadP = [&](int t) {
#pragma unroll
    for (int r = 0; r < 4; ++r) {
      int row = q * 4 + r;
      pr[r] = cvalid ? prices[((size_t)(b0 + row) * TT + t) * SS + col] : 0.f;
    }
  };

  // LN epilogue: 2 LDS-only barriers. Stats: lanes<16 read cross-wave
  // partials, then in-wave shuffle broadcast.
  auto ln_epi = [&](f32x4& a0, f32x4& a1, float bv0, float bv1, float gv0, float gv1,
                    float ev0, float ev1, short (*dst)[HH + 8]) {
    float p1[4], p2[4];
#pragma unroll
    for (int r = 0; r < 4; ++r) {
      float v0 = a0[r] + bv0;
      float v1 = a1[r] + bv1;
      a0[r] = v0;
      a1[r] = v1;
      p1[r] = v0 + v1;
      p2[r] = v0 * v0 + v1 * v1;
    }
#pragma unroll
    for (int m = 1; m <= 8; m <<= 1)
#pragma unroll
      for (int r = 0; r < 4; ++r) {
        p1[r] += __shfl_xor(p1[r], m);
        p2[r] += __shfl_xor(p2[r], m);
      }
    if (c16 == 0) {
#pragma unroll
      for (int r = 0; r < 4; ++r) {
        lnred[q * 4 + r][2 * w] = p1[r];
        lnred[q * 4 + r][2 * w + 1] = p2[r];
      }
    }
    bar_lds();
    float meanv = 0.f, rstdv = 0.f;
    if (lane < 16) {
      float S1 = 0.f, S2 = 0.f;
#pragma unroll
      for (int i = 0; i < 8; ++i) {
        S1 += lnred[lane][2 * i];
        S2 += lnred[lane][2 * i + 1];
      }
      meanv = S1 * (1.f / HH);
      float var = fmaxf(S2 * (1.f / HH) - meanv * meanv, 0.f);
      rstdv = rsqrtf(var + 1e-5f);
    }
#pragma unroll
    for (int r = 0; r < 4; ++r) {
      int row = q * 4 + r;
      float mean = __shfl(meanv, row);
      float rstd = __shfl(rstdv, row);
      float v0 = (a0[r] - mean) * rstd * gv0 + ev0;
      float v1 = (a1[r] - mean) * rstd * gv1 + ev1;
      dst[row][n0] = f2b(fmaxf(v0, 0.f));
      dst[row][n1] = f2b(fmaxf(v1, 0.f));
    }
    bar_lds();
  };

  loadW1(0);
  loadP(0);
  float costreg = 0.f;

  for (int t = 0; t < NSTEP; ++t) {
    // hoist step-t params (vector loads issued early, overlap GEMM1)
    const float b1v0 = b1[t * HH + n0], b1v1 = b1[t * HH + n1];
    const float g1v0 = g1[t * HH + n0], g1v1 = g1[t * HH + n1];
    const float e1v0 = be1[t * HH + n0], e1v1 = be1[t * HH + n1];
    const float b2v0 = b2[t * HH + n0], b2v1 = b2[t * HH + n1];
    const float g2v0 = g2[t * HH + n0], g2v1 = g2[t * HH + n1];
    const float e2v0 = be2[t * HH + n0], e2v1 = be2[t * HH + n1];
    const float bov = cvalid ? bo[t * SS + col] : 0.f;

    // ===== GEMM1: h1[16x256] = s @ W1[t].T (weights already in regs) =====
    f32x4 acc0 = (f32x4){0.f, 0.f, 0.f, 0.f};
    f32x4 acc1 = (f32x4){0.f, 0.f, 0.f, 0.f};
#pragma unroll
    for (int ks = 0; ks < 4; ++ks) {
      bf16x8 a = *(const bf16x8*)&sbuf[c16][ks * 32 + q * 8];
      acc0 = MFMA(a, w1f[2 * ks + 0], acc0);
      acc1 = MFMA(a, w1f[2 * ks + 1], acc1);
    }

    // prefetch W2[t]; stays in flight across LN1's barriers
    bf16x8 w2f[16];
#pragma unroll
    for (int ks = 0; ks < 8; ++ks) {
      const int k = ks * 32 + q * 8;
      if (MODE == 0) {
        w2f[2 * ks + 0] = *(const bf16x8*)&W2b[((size_t)t * HH + n0) * HH + k];
        w2f[2 * ks + 1] = *(const bf16x8*)&W2b[((size_t)t * HH + n1) * HH + k];
      } else {
        w2f[2 * ks + 0] = cvt8(W2f + ((size_t)t * HH + n0) * HH + k);
        w2f[2 * ks + 1] = cvt8(W2f + ((size_t)t * HH + n1) * HH + k);
      }
    }

    ln_epi(acc0, acc1, b1v0, b1v1, g1v0, g1v1, e1v0, e1v1, xb1);

    // ===== GEMM2: h2[16x256] = x1 @ W2[t].T =====
    acc0 = (f32x4){0.f, 0.f, 0.f, 0.f};
    acc1 = (f32x4){0.f, 0.f, 0.f, 0.f};
#pragma unroll
    for (int ks = 0; ks < 8; ++ks) {
      bf16x8 a = *(const bf16x8*)&xb1[c16][ks * 32 + q * 8];
      acc0 = MFMA(a, w2f[2 * ks + 0], acc0);
      acc1 = MFMA(a, w2f[2 * ks + 1], acc1);
    }

    // prefetch Wo[t]; stays in flight across LN2's barriers
    bf16x8 wof[8];
#pragma unroll
    for (int ks = 0; ks < 8; ++ks) {
      const int k = ks * 32 + q * 8;
      if (MODE == 0) {
        wof[ks] = *(const bf16x8*)&Wob[((size_t)t * NO + col) * HH + k];
      } else {
        if (cvalid) {
          wof[ks] = cvt8(Wof + ((size_t)t * SS + col) * HH + k);
        } else {
          bf16x8 z = {0, 0, 0, 0, 0, 0, 0, 0};
          wof[ks] = z;
        }
      }
    }

    ln_epi(acc0, acc1, b2v0, b2v1, g2v0, g2v1, e2v0, e2v1, xb2);

    // ===== GEMM3: o[16x(100p128)] = x2 @ Wo[t].T =====
    f32x4 a3 = (f32x4){0.f, 0.f, 0.f, 0.f};
#pragma unroll
    for (int ks = 0; ks < 8; ++ks) {
      bf16x8 a = *(const bf16x8*)&xb2[c16][ks * 32 + q * 8];
      a3 = MFMA(a, wof[ks], a3);
    }

    // prefetch W1[t+1] + prices[t+1]; stays in flight across epilogue barrier
    float pcur[4];
#pragma unroll
    for (int r = 0; r < 4; ++r) pcur[r] = pr[r];
    const int tn = (t + 1 < NSTEP) ? t + 1 : 0;
    loadW1(tn);
    loadP(t + 1);  // at t=48 this loads p_T for the terminal term

    // ===== epilogue: a = min(o+bo, s); cost += p*a + 0.01*(p*a)^2; s -= a =====
#pragma unroll
    for (int r = 0; r < 4; ++r) {
      float o = a3[r] + bov;
      float a = fminf(o, s_reg[r]);
      float pa = pcur[r] * a;
      costreg += pa + 0.01f * pa * pa;
      s_reg[r] -= a;
      if (cvalid) sbuf[q * 4 + r][col] = f2b(s_reg[r]);
    }
    bar_lds();
  }

  // ===== terminal: cost += p_T*s + 0.01*(p_T*s)^2 (pr holds t=49 prices) =====
#pragma unroll
  for (int r = 0; r < 4; ++r) {
    float pa = pr[r] * s_reg[r];
    costreg += pa + 0.01f * pa * pa;
  }

#pragma unroll
  for (int m = 1; m < 64; m <<= 1) costreg += __shfl_xor(costreg, m);
  if (lane == 0) wsum[w] = costreg;
  __syncthreads();
  if (tid == 0) {
    float tot = 0.f;
#pragma unroll
    for (int i = 0; i < 8; ++i) tot += wsum[i];
    atomicAdd(out, tot * (1.f / NBATCH));
  }
}

extern "C" void kernel_launch(void* const* d_in, const int* in_sizes, int n_in,
                              void* d_out, int out_size, void* d_ws, size_t ws_size,
                              hipStream_t stream) {
  const float* s0 = (const float*)d_in[0];
  const float* prices = (const float*)d_in[1];
  const float* W1 = (const float*)d_in[2];
  const float* b1 = (const float*)d_in[3];
  const float* g1 = (const float*)d_in[4];
  const float* be1 = (const float*)d_in[5];
  const float* W2 = (const float*)d_in[6];
  const float* b2 = (const float*)d_in[7];
  const float* g2 = (const float*)d_in[8];
  const float* be2 = (const float*)d_in[9];
  const float* Wo = (const float*)d_in[10];
  const float* bo = (const float*)d_in[11];
  float* out = (float*)d_out;

  const size_t nW1 = (size_t)TT * HH * K1;
  const size_t nW2 = (size_t)TT * HH * HH;
  const size_t nWo = (size_t)TT * NO * HH;
  const size_t need = (nW1 + nW2 + nWo) * sizeof(short);

  if (ws_size >= need) {
    short* W1b = (short*)d_ws;
    short* W2b = W1b + nW1;
    short* Wob = W2b + nW2;
    prep<<<dim3(1024), dim3(256), 0, stream>>>(W1, W2, Wo, W1b, W2b, Wob, out);
    run_kernel<0><<<dim3(NBLK), dim3(NTHR), 0, stream>>>(
        s0, prices, b1, g1, be1, b2, g2, be2, bo,
        W1, W2, Wo, W1b, W2b, Wob, out);
  } else {
    zero_out<<<dim3(1), dim3(64), 0, stream>>>(out);
    run_kernel<1><<<dim3(NBLK), dim3(NTHR), 0, stream>>>(
        s0, prices, b1, g1, be1, b2, g2, be2, bo,
        W1, W2, Wo, (const short*)nullptr, (const short*)nullptr, (const short*)nullptr, out);
  }
}

// Round 4
// 402.565 us; speedup vs baseline: 1.2643x; 1.2643x over previous
//
#include <hip/hip_runtime.h>
#include <stdint.h>

#define TT 50
#define NSTEP 49
#define NBATCH 4096
#define SS 100
#define HH 256
#define K1 128      // padded K for GEMM1 (S=100 -> 128)
#define NO 128      // padded N for GEMM3 (C=100 -> 128)
#define MROWS 16
#define NBLK 256
#define NTHR 512    // 8 waves

typedef short bf16x8 __attribute__((ext_vector_type(8)));
typedef float f32x4 __attribute__((ext_vector_type(4)));

#define MFMA(a, b, c) __builtin_amdgcn_mfma_f32_16x16x32_bf16((a), (b), (c), 0, 0, 0)

// Fragment-linear weight layout group counts (16B per lane per group):
//   W1: [t][nt=16][ks=4][lane=64][8]   -> 4096 groups/t
//   W2: [t][nt=16][ks=8][lane=64][8]   -> 8192 groups/t
//   Wo: [t][nt=8 ][ks=8][lane=64][8]   -> 4096 groups/t
#define G1N (TT * 16 * 4 * 64)
#define G2N (TT * 16 * 8 * 64)
#define G3N (TT * 8 * 8 * 64)

// LDS-only barrier: waits ds ops but does not drain vmcnt.
__device__ __forceinline__ void bar_lds() {
  __asm__ volatile("s_waitcnt lgkmcnt(0)\n\ts_barrier" ::: "memory");
}

__device__ __forceinline__ short f2b(float f) {
  union { float f; uint32_t u; } v;
  v.f = f;
  return (short)((v.u + 0x7FFFu + ((v.u >> 16) & 1u)) >> 16);
}

__device__ __forceinline__ bf16x8 cvt8(const float* __restrict__ p) {
  bf16x8 r;
#pragma unroll
  for (int j = 0; j < 8; ++j) r[j] = f2b(p[j]);
  return r;
}

__device__ __forceinline__ bf16x8 ldpad(const float* __restrict__ rowp, int k, int kmax) {
  bf16x8 r;
#pragma unroll
  for (int j = 0; j < 8; ++j) {
    int kk = k + j;
    r[j] = (kk < kmax) ? f2b(rowp[kk]) : (short)0;
  }
  return r;
}

__global__ void zero_out(float* out) {
  if (threadIdx.x == 0 && blockIdx.x == 0) out[0] = 0.f;
}

// fp32 -> bf16 weight conversion into MFMA fragment-linear order so the main
// kernel's weight loads are lane-contiguous (1KB coalesced per wave-load,
// 8 cache lines instead of 64). One thread per 16B output group.
__global__ void prep(const float* __restrict__ W1, const float* __restrict__ W2,
                     const float* __restrict__ Wo,
                     short* __restrict__ W1g, short* __restrict__ W2g, short* __restrict__ Wog,
                     float* __restrict__ out) {
  const int g = blockIdx.x * blockDim.x + threadIdx.x;
  if (g < G1N) {
    const int t = g >> 12;            // /4096
    const int rem = g & 4095;
    const int nt = rem >> 8;          // /256
    const int ks = (rem >> 6) & 3;
    const int lane = rem & 63;
    const int q = lane >> 4, c16 = lane & 15;
    const int n = nt * 16 + c16;
    const int kb = ks * 32 + q * 8;
    const float* src = W1 + ((size_t)t * HH + n) * SS;
    bf16x8 v;
#pragma unroll
    for (int j = 0; j < 8; ++j) {
      int k = kb + j;
      v[j] = (k < SS) ? f2b(src[k]) : (short)0;
    }
    *(bf16x8*)&W1g[(size_t)g * 8] = v;
  } else if (g < G1N + G2N) {
    const int h = g - G1N;
    const int t = h >> 13;            // /8192
    const int rem = h & 8191;
    const int nt = rem >> 9;          // /512
    const int ks = (rem >> 6) & 7;
    const int lane = rem & 63;
    const int q = lane >> 4, c16 = lane & 15;
    const int n = nt * 16 + c16;
    const int kb = ks * 32 + q * 8;
    const float* src = W2 + ((size_t)t * HH + n) * HH + kb;
    bf16x8 v;
#pragma unroll
    for (int j = 0; j < 8; ++j) v[j] = f2b(src[j]);
    *(bf16x8*)&W2g[(size_t)h * 8] = v;
  } else if (g < G1N + G2N + G3N) {
    const int h = g - G1N - G2N;
    const int t = h >> 12;            // /4096
    const int rem = h & 4095;
    const int nt = rem >> 9;          // /512
    const int ks = (rem >> 6) & 7;
    const int lane = rem & 63;
    const int q = lane >> 4, c16 = lane & 15;
    const int n = nt * 16 + c16;
    const int kb = ks * 32 + q * 8;
    bf16x8 v;
    if (n < SS) {
      const float* src = Wo + ((size_t)t * SS + n) * HH + kb;
#pragma unroll
      for (int j = 0; j < 8; ++j) v[j] = f2b(src[j]);
    } else {
      bf16x8 z = {0, 0, 0, 0, 0, 0, 0, 0};
      v = z;
    }
    *(bf16x8*)&Wog[(size_t)h * 8] = v;
  }
  if (g == 0) out[0] = 0.f;
}

// Persistent kernel: each block owns MROWS batch rows for all NSTEP steps.
// s carry in per-thread registers; cost in a register accumulator.
template <int MODE>
__global__ __launch_bounds__(NTHR, 2) void run_kernel(
    const float* __restrict__ s0, const float* __restrict__ prices,
    const float* __restrict__ b1, const float* __restrict__ g1, const float* __restrict__ be1,
    const float* __restrict__ b2, const float* __restrict__ g2, const float* __restrict__ be2,
    const float* __restrict__ bo,
    const float* __restrict__ W1f, const float* __restrict__ W2f, const float* __restrict__ Wof,
    const short* __restrict__ W1g, const short* __restrict__ W2g, const short* __restrict__ Wog,
    float* __restrict__ out) {
  __shared__ short sbuf[MROWS][K1 + 8];   // bf16 s, K-padded
  __shared__ short xb1[MROWS][HH + 8];
  __shared__ short xb2[MROWS][HH + 8];
  __shared__ float lnred[MROWS][17];
  __shared__ float wsum[8];

  const int tid = threadIdx.x;
  const int w = tid >> 6;
  const int lane = tid & 63;
  const int q = lane >> 4;
  const int c16 = lane & 15;
  const int b0 = blockIdx.x * MROWS;

  const int n0 = w * 32 + c16;   // GEMM1/2 n-tile cols (tiles 2w, 2w+1)
  const int n1 = n0 + 16;
  const int col = w * 16 + c16;  // GEMM3 / epilogue col (tile w)
  const bool cvalid = col < SS;

  for (int j = tid; j < MROWS * (K1 + 8); j += NTHR) ((short*)sbuf)[j] = 0;
  __syncthreads();

  float s_reg[4];
#pragma unroll
  for (int r = 0; r < 4; ++r) {
    int row = q * 4 + r;
    s_reg[r] = cvalid ? s0[(size_t)(b0 + row) * SS + col] : 0.f;
    if (cvalid) sbuf[row][col] = f2b(s_reg[r]);
  }
  __syncthreads();

  bf16x8 w1f[8];
  auto loadW1 = [&](int t) {
#pragma unroll
    for (int ks = 0; ks < 4; ++ks) {
      if (MODE == 0) {
        w1f[2 * ks + 0] = *(const bf16x8*)&W1g[((((size_t)t * 16 + 2 * w) * 4 + ks) * 64 + lane) * 8];
        w1f[2 * ks + 1] = *(const bf16x8*)&W1g[((((size_t)t * 16 + 2 * w + 1) * 4 + ks) * 64 + lane) * 8];
      } else {
        const int k = ks * 32 + q * 8;
        w1f[2 * ks + 0] = ldpad(W1f + ((size_t)t * HH + n0) * SS, k, SS);
        w1f[2 * ks + 1] = ldpad(W1f + ((size_t)t * HH + n1) * SS, k, SS);
      }
    }
  };
  float pr[4];
  auto loadP = [&](int t) {
#pragma unroll
    for (int r = 0; r < 4; ++r) {
      int row = q * 4 + r;
      pr[r] = cvalid ? prices[((size_t)(b0 + row) * TT + t) * SS + col] : 0.f;
    }
  };

  // LN epilogue: shuffle butterfly + LDS cross-wave stats, 2 LDS-only barriers.
  auto ln_epi = [&](f32x4& a0, f32x4& a1, float bv0, float bv1, float gv0, float gv1,
                    float ev0, float ev1, short (*dst)[HH + 8]) {
    float p1[4], p2[4];
#pragma unroll
    for (int r = 0; r < 4; ++r) {
      float v0 = a0[r] + bv0;
      float v1 = a1[r] + bv1;
      a0[r] = v0;
      a1[r] = v1;
      p1[r] = v0 + v1;
      p2[r] = v0 * v0 + v1 * v1;
    }
#pragma unroll
    for (int m = 1; m <= 8; m <<= 1)
#pragma unroll
      for (int r = 0; r < 4; ++r) {
        p1[r] += __shfl_xor(p1[r], m);
        p2[r] += __shfl_xor(p2[r], m);
      }
    if (c16 == 0) {
#pragma unroll
      for (int r = 0; r < 4; ++r) {
        lnred[q * 4 + r][2 * w] = p1[r];
        lnred[q * 4 + r][2 * w + 1] = p2[r];
      }
    }
    bar_lds();
    float meanv = 0.f, rstdv = 0.f;
    if (lane < 16) {
      float S1 = 0.f, S2 = 0.f;
#pragma unroll
      for (int i = 0; i < 8; ++i) {
        S1 += lnred[lane][2 * i];
        S2 += lnred[lane][2 * i + 1];
      }
      meanv = S1 * (1.f / HH);
      float var = fmaxf(S2 * (1.f / HH) - meanv * meanv, 0.f);
      rstdv = rsqrtf(var + 1e-5f);
    }
#pragma unroll
    for (int r = 0; r < 4; ++r) {
      int row = q * 4 + r;
      float mean = __shfl(meanv, row);
      float rstd = __shfl(rstdv, row);
      float v0 = (a0[r] - mean) * rstd * gv0 + ev0;
      float v1 = (a1[r] - mean) * rstd * gv1 + ev1;
      dst[row][n0] = f2b(fmaxf(v0, 0.f));
      dst[row][n1] = f2b(fmaxf(v1, 0.f));
    }
    bar_lds();
  };

  loadW1(0);
  loadP(0);
  float costreg = 0.f;

  for (int t = 0; t < NSTEP; ++t) {
    const float b1v0 = b1[t * HH + n0], b1v1 = b1[t * HH + n1];
    const float g1v0 = g1[t * HH + n0], g1v1 = g1[t * HH + n1];
    const float e1v0 = be1[t * HH + n0], e1v1 = be1[t * HH + n1];
    const float b2v0 = b2[t * HH + n0], b2v1 = b2[t * HH + n1];
    const float g2v0 = g2[t * HH + n0], g2v1 = g2[t * HH + n1];
    const float e2v0 = be2[t * HH + n0], e2v1 = be2[t * HH + n1];
    const float bov = cvalid ? bo[t * SS + col] : 0.f;

    // ===== GEMM1: h1[16x256] = s @ W1[t].T =====
    f32x4 acc0 = (f32x4){0.f, 0.f, 0.f, 0.f};
    f32x4 acc1 = (f32x4){0.f, 0.f, 0.f, 0.f};
#pragma unroll
    for (int ks = 0; ks < 4; ++ks) {
      bf16x8 a = *(const bf16x8*)&sbuf[c16][ks * 32 + q * 8];
      acc0 = MFMA(a, w1f[2 * ks + 0], acc0);
      acc1 = MFMA(a, w1f[2 * ks + 1], acc1);
    }

    // W2[t] fragment loads (coalesced 1KB wave-loads)
    bf16x8 w2f[16];
#pragma unroll
    for (int ks = 0; ks < 8; ++ks) {
      if (MODE == 0) {
        w2f[2 * ks + 0] = *(const bf16x8*)&W2g[((((size_t)t * 16 + 2 * w) * 8 + ks) * 64 + lane) * 8];
        w2f[2 * ks + 1] = *(const bf16x8*)&W2g[((((size_t)t * 16 + 2 * w + 1) * 8 + ks) * 64 + lane) * 8];
      } else {
        const int k = ks * 32 + q * 8;
        w2f[2 * ks + 0] = cvt8(W2f + ((size_t)t * HH + n0) * HH + k);
        w2f[2 * ks + 1] = cvt8(W2f + ((size_t)t * HH + n1) * HH + k);
      }
    }

    ln_epi(acc0, acc1, b1v0, b1v1, g1v0, g1v1, e1v0, e1v1, xb1);

    // ===== GEMM2: h2[16x256] = x1 @ W2[t].T (split acc chains) =====
    f32x4 acc0b = (f32x4){0.f, 0.f, 0.f, 0.f};
    f32x4 acc1b = (f32x4){0.f, 0.f, 0.f, 0.f};
    acc0 = (f32x4){0.f, 0.f, 0.f, 0.f};
    acc1 = (f32x4){0.f, 0.f, 0.f, 0.f};
#pragma unroll
    for (int ks = 0; ks < 4; ++ks) {
      bf16x8 a = *(const bf16x8*)&xb1[c16][ks * 32 + q * 8];
      acc0 = MFMA(a, w2f[2 * ks + 0], acc0);
      acc1 = MFMA(a, w2f[2 * ks + 1], acc1);
    }
#pragma unroll
    for (int ks = 4; ks < 8; ++ks) {
      bf16x8 a = *(const bf16x8*)&xb1[c16][ks * 32 + q * 8];
      acc0b = MFMA(a, w2f[2 * ks + 0], acc0b);
      acc1b = MFMA(a, w2f[2 * ks + 1], acc1b);
    }
    acc0 = acc0 + acc0b;
    acc1 = acc1 + acc1b;

    // Wo[t] fragment loads
    bf16x8 wof[8];
#pragma unroll
    for (int ks = 0; ks < 8; ++ks) {
      if (MODE == 0) {
        wof[ks] = *(const bf16x8*)&Wog[((((size_t)t * 8 + w) * 8 + ks) * 64 + lane) * 8];
      } else {
        const int k = ks * 32 + q * 8;
        if (cvalid) {
          wof[ks] = cvt8(Wof + ((size_t)t * SS + col) * HH + k);
        } else {
          bf16x8 z = {0, 0, 0, 0, 0, 0, 0, 0};
          wof[ks] = z;
        }
      }
    }

    ln_epi(acc0, acc1, b2v0, b2v1, g2v0, g2v1, e2v0, e2v1, xb2);

    // ===== GEMM3: o[16x(100p128)] = x2 @ Wo[t].T (split acc chains) =====
    f32x4 a3 = (f32x4){0.f, 0.f, 0.f, 0.f};
    f32x4 a3b = (f32x4){0.f, 0.f, 0.f, 0.f};
#pragma unroll
    for (int ks = 0; ks < 4; ++ks) {
      bf16x8 a = *(const bf16x8*)&xb2[c16][ks * 32 + q * 8];
      a3 = MFMA(a, wof[ks], a3);
    }
#pragma unroll
    for (int ks = 4; ks < 8; ++ks) {
      bf16x8 a = *(const bf16x8*)&xb2[c16][ks * 32 + q * 8];
      a3b = MFMA(a, wof[ks], a3b);
    }
    a3 = a3 + a3b;

    // next-step W1 + prices
    float pcur[4];
#pragma unroll
    for (int r = 0; r < 4; ++r) pcur[r] = pr[r];
    const int tn = (t + 1 < NSTEP) ? t + 1 : 0;
    loadW1(tn);
    loadP(t + 1);

    // ===== epilogue =====
#pragma unroll
    for (int r = 0; r < 4; ++r) {
      float o = a3[r] + bov;
      float a = fminf(o, s_reg[r]);
      float pa = pcur[r] * a;
      costreg += pa + 0.01f * pa * pa;
      s_reg[r] -= a;
      if (cvalid) sbuf[q * 4 + r][col] = f2b(s_reg[r]);
    }
    bar_lds();
  }

  // ===== terminal =====
#pragma unroll
  for (int r = 0; r < 4; ++r) {
    float pa = pr[r] * s_reg[r];
    costreg += pa + 0.01f * pa * pa;
  }

#pragma unroll
  for (int m = 1; m < 64; m <<= 1) costreg += __shfl_xor(costreg, m);
  if (lane == 0) wsum[w] = costreg;
  __syncthreads();
  if (tid == 0) {
    float tot = 0.f;
#pragma unroll
    for (int i = 0; i < 8; ++i) tot += wsum[i];
    atomicAdd(out, tot * (1.f / NBATCH));
  }
}

extern "C" void kernel_launch(void* const* d_in, const int* in_sizes, int n_in,
                              void* d_out, int out_size, void* d_ws, size_t ws_size,
                              hipStream_t stream) {
  const float* s0 = (const float*)d_in[0];
  const float* prices = (const float*)d_in[1];
  const float* W1 = (const float*)d_in[2];
  const float* b1 = (const float*)d_in[3];
  const float* g1 = (const float*)d_in[4];
  const float* be1 = (const float*)d_in[5];
  const float* W2 = (const float*)d_in[6];
  const float* b2 = (const float*)d_in[7];
  const float* g2 = (const float*)d_in[8];
  const float* be2 = (const float*)d_in[9];
  const float* Wo = (const float*)d_in[10];
  const float* bo = (const float*)d_in[11];
  float* out = (float*)d_out;

  const size_t need = ((size_t)G1N + G2N + G3N) * 8 * sizeof(short);

  if (ws_size >= need) {
    short* W1g = (short*)d_ws;
    short* W2g = W1g + (size_t)G1N * 8;
    short* Wog = W2g + (size_t)G2N * 8;
    const int ngroups = G1N + G2N + G3N;           // 819200
    prep<<<dim3((ngroups + 255) / 256), dim3(256), 0, stream>>>(W1, W2, Wo, W1g, W2g, Wog, out);
    run_kernel<0><<<dim3(NBLK), dim3(NTHR), 0, stream>>>(
        s0, prices, b1, g1, be1, b2, g2, be2, bo,
        W1, W2, Wo, W1g, W2g, Wog, out);
  } else {
    zero_out<<<dim3(1), dim3(64), 0, stream>>>(out);
    run_kernel<1><<<dim3(NBLK), dim3(NTHR), 0, stream>>>(
        s0, prices, b1, g1, be1, b2, g2, be2, bo,
        W1, W2, Wo, (const short*)nullptr, (const short*)nullptr, (const short*)nullptr, out);
  }
}